// Round 9
// baseline (247.524 us; speedup 1.0000x reference)
//
#include <hip/hip_runtime.h>
#include <hip/hip_bf16.h>
#include <math.h>
#include <stdint.h>

typedef _Float16 f16;
typedef _Float16 f16x8 __attribute__((ext_vector_type(8)));
typedef float f32x16 __attribute__((ext_vector_type(16)));

#define DIM 256
#define LOSCALE 2048.0f
#define INV_LOSCALE (1.0f/2048.0f)

// B' stream: 4096 codes x 256 depth x {hi,lo}, fragment-major:
// byte offset = col*32768 + s*2048 + t*1024 + lane*16
// (col 0..127 = 32 codes each, k-step s 0..15, t 0:hi 1:lo)
// lane l holds 16B = e[code=col*32+(l&31)][depth=s*16+(l>>5)*8 .. +8]
// Unit = half-col = 16KB (s 0..7 or 8..15). 32KB pad for uniform tail staging.
#define BP_BYTES (4096u*1024u + 32768u)

#define GLOAD16(gp, lp) __builtin_amdgcn_global_load_lds( \
    (const __attribute__((address_space(1))) void*)(gp),  \
    (__attribute__((address_space(3))) void*)(lp), 16, 0, 0)

// ---------------------------------------------------------------------------
// pack codebook into fragment-major hi/lo f16 stream
// ---------------------------------------------------------------------------
__global__ void vq_pack2(const float* __restrict__ emb, f16* __restrict__ bp)
{
    int o = blockIdx.x * blockDim.x + threadIdx.x;   // one per 16B chunk, 262144
    int l = o & 63;
    int b = o >> 6;
    int t   = b & 1;
    int s   = (b >> 1) & 15;
    int col = b >> 5;
    int code  = col * 32 + (l & 31);
    int depth = s * 16 + (l >> 5) * 8;
    const float* gp = emb + (size_t)code * DIM + depth;
    float4 x0 = *(const float4*)gp;
    float4 x1 = *(const float4*)(gp + 4);
    float xs[8] = {x0.x, x0.y, x0.z, x0.w, x1.x, x1.y, x1.z, x1.w};
    f16x8 v;
    #pragma unroll
    for (int j = 0; j < 8; ++j) {
        f16 h = (f16)xs[j];
        v[j] = t ? (f16)((xs[j] - (float)h) * LOSCALE) : h;
    }
    *(f16x8*)(bp + (size_t)o * 8) = v;
}

// ||e_k||^2, one 64-thread block per code (fp32, full precision)
__global__ void vq_e2(const float* __restrict__ emb, float* __restrict__ e2) {
    int k = blockIdx.x;
    int l = threadIdx.x;
    float4 v = ((const float4*)(emb + (size_t)k * DIM))[l];
    float s = v.x * v.x + v.y * v.y + v.z * v.z + v.w * v.w;
    #pragma unroll
    for (int off = 32; off; off >>= 1) s += __shfl_xor(s, off);
    if (l == 0) e2[k] = s;
}

__global__ void vq_zero(int* __restrict__ p, int n) {
    int i = blockIdx.x * blockDim.x + threadIdx.x;
    if (i < n) p[i] = 0;
}

// ---------------------------------------------------------------------------
// MFMA argmin, M=64/wave: each wave owns TWO 32-row tiles (a0, a1) so every
// B fragment pair (bh,bl) feeds 6 back-to-back MFMAs (192 cyc pipe cover per
// 2 ds_reads) -- one wave streams its SIMD matrix pipe; designed for
// 1 wave/SIMD (A hi/lo = 256 regs). Block: 4 waves x 64 rows = 256 rows,
// one code half (2048 codes = 128 units of 8 k-steps). 4 x 16KB B-buffers,
// counted vmcnt(8), raw s_barrier (never drains in main loop).
// ---------------------------------------------------------------------------
__global__ __launch_bounds__(256, 1) void vq_argmin8(
    const float* __restrict__ z, const char* __restrict__ bp,
    const float* __restrict__ e2, unsigned long long* __restrict__ part)
{
    __shared__ __align__(16) char bufs[4][16384];   // 64 KB
    __shared__ float e2s[2048];                     // 8 KB

    const int t    = threadIdx.x;
    const int lane = t & 63;
    const int rt   = t >> 6;               // wave 0..3
    const int hw   = blockIdx.x & 1;       // code half
    const int rg   = blockIdx.x >> 1;      // row group (256 rows)
    const int l31  = lane & 31;
    const int hi5  = lane >> 5;
    const int rowbase = rg * 256 + rt * 64;

    // ---- e2 half to LDS ----
    *(float4*)&e2s[t * 8]     = *(const float4*)(e2 + hw * 2048 + t * 8);
    *(float4*)&e2s[t * 8 + 4] = *(const float4*)(e2 + hw * 2048 + t * 8 + 4);

    // ---- A panel (2 x 32 rows) to registers, hi/lo split ----
    f16x8 a_h0[16], a_l0[16], a_h1[16], a_l1[16];
    {
        const float* zr0 = z + (size_t)(rowbase + l31) * DIM + hi5 * 8;
        const float* zr1 = z + (size_t)(rowbase + 32 + l31) * DIM + hi5 * 8;
        #pragma unroll
        for (int s = 0; s < 16; ++s) {
            float4 x0 = *(const float4*)(zr0 + s * 16);
            float4 x1 = *(const float4*)(zr0 + s * 16 + 4);
            float4 y0 = *(const float4*)(zr1 + s * 16);
            float4 y1 = *(const float4*)(zr1 + s * 16 + 4);
            float xs[8] = {x0.x, x0.y, x0.z, x0.w, x1.x, x1.y, x1.z, x1.w};
            float ys[8] = {y0.x, y0.y, y0.z, y0.w, y1.x, y1.y, y1.z, y1.w};
            #pragma unroll
            for (int j = 0; j < 8; ++j) {
                f16 h0 = (f16)xs[j];
                a_h0[s][j] = h0;
                a_l0[s][j] = (f16)((xs[j] - (float)h0) * LOSCALE);
                f16 h1 = (f16)ys[j];
                a_h1[s][j] = h1;
                a_l1[s][j] = (f16)((ys[j] - (float)h1) * LOSCALE);
            }
        }
    }
    __syncthreads();   // e2s visible; all pre-loop vmem drained

    float    bestd0[16], bestd1[16];
    unsigned bc0[4], bc1[4];
    #pragma unroll
    for (int q = 0; q < 16; ++q) { bestd0[q] = 3.4e38f; bestd1[q] = 3.4e38f; }
    #pragma unroll
    for (int i = 0; i < 4; ++i) { bc0[i] = 0u; bc1[i] = 0u; }

    const char* bhalf = bp + ((size_t)hw << 21);   // 2 MB half

    // stage unit uu (16KB) into buffer pb: 256 thr x 4 x 16B, linear
#define STAGE(pb, uu) do {                                                    \
    const char* src_ = bhalf + ((size_t)(uu) << 14) + (size_t)t * 16;         \
    char* dst_ = bufs[pb] + t * 16;                                           \
    _Pragma("unroll")                                                         \
    for (int i_ = 0; i_ < 4; ++i_)                                            \
        GLOAD16(src_ + i_ * 4096, dst_ + i_ * 4096);                          \
    } while (0)

    // compute 8 k-steps from buffer BB with A-base SB, 1-ahead read pipeline
#define COMPUTE8(BB, SB) do {                                                 \
    const char* bbp_ = (BB);                                                  \
    f16x8 bh_ = *(const f16x8*)(bbp_ + lane * 16);                            \
    f16x8 bl_ = *(const f16x8*)(bbp_ + 1024 + lane * 16);                     \
    __builtin_amdgcn_s_setprio(1);                                            \
    _Pragma("unroll")                                                         \
    for (int sl_ = 0; sl_ < 8; ++sl_) {                                       \
        f16x8 bhn_, bln_;                                                     \
        if (sl_ < 7) {                                                        \
            bhn_ = *(const f16x8*)(bbp_ + (sl_+1) * 2048 + lane * 16);        \
            bln_ = *(const f16x8*)(bbp_ + (sl_+1) * 2048 + 1024 + lane * 16); \
        }                                                                     \
        acc0_0 = __builtin_amdgcn_mfma_f32_32x32x16_f16(a_h0[(SB)+sl_], bh_, acc0_0, 0,0,0); \
        acc0_1 = __builtin_amdgcn_mfma_f32_32x32x16_f16(a_h1[(SB)+sl_], bh_, acc0_1, 0,0,0); \
        f32x16 t0_ = __builtin_amdgcn_mfma_f32_32x32x16_f16(a_h0[(SB)+sl_], bl_, acc1_0, 0,0,0); \
        f32x16 t1_ = __builtin_amdgcn_mfma_f32_32x32x16_f16(a_h1[(SB)+sl_], bl_, acc1_1, 0,0,0); \
        acc1_0 = __builtin_amdgcn_mfma_f32_32x32x16_f16(a_l0[(SB)+sl_], bh_, t0_, 0,0,0); \
        acc1_1 = __builtin_amdgcn_mfma_f32_32x32x16_f16(a_l1[(SB)+sl_], bh_, t1_, 0,0,0); \
        if (sl_ < 7) { bh_ = bhn_; bl_ = bln_; }                              \
    }                                                                         \
    __builtin_amdgcn_s_setprio(0);                                            \
    } while (0)

#define PHASE_SYNC() do {                                                     \
    asm volatile("s_waitcnt vmcnt(8)" ::: "memory");                          \
    asm volatile("s_waitcnt lgkmcnt(0)" ::: "memory");                        \
    __builtin_amdgcn_s_barrier();                                             \
    __builtin_amdgcn_sched_barrier(0);                                        \
    } while (0)

    STAGE(0, 0);
    STAGE(1, 1);

    for (int c = 0; c < 64; ++c) {
        f32x16 acc0_0, acc0_1, acc1_0, acc1_1;
        #pragma unroll
        for (int q = 0; q < 16; ++q) {
            acc0_0[q] = 0.0f; acc0_1[q] = 0.0f; acc1_0[q] = 0.0f; acc1_1[q] = 0.0f;
        }

        // phase 0: unit 2c (s 0..7); stage unit 2c+2
        STAGE((2*c + 2) & 3, 2*c + 2);
        PHASE_SYNC();
        COMPUTE8(bufs[(2*c) & 3], 0);

        // phase 1: unit 2c+1 (s 8..15); stage unit 2c+3
        STAGE((2*c + 3) & 3, 2*c + 3);
        PHASE_SYNC();
        COMPUTE8(bufs[(2*c + 1) & 3], 8);

        // epilogue: fold scales, distances, running argmin (both m-tiles)
        float e2c = e2s[c * 32 + l31];
        #pragma unroll
        for (int q = 0; q < 16; ++q) {
            const unsigned sh = (unsigned)((q & 3) * 8);
            float dot0  = fmaf(acc1_0[q], INV_LOSCALE, acc0_0[q]);
            float dist0 = fmaf(-2.0f, dot0, e2c);
            bool  lt0   = dist0 < bestd0[q];
            bestd0[q]   = lt0 ? dist0 : bestd0[q];
            unsigned nv0 = (bc0[q >> 2] & ~(0xFFu << sh)) | ((unsigned)c << sh);
            bc0[q >> 2]  = lt0 ? nv0 : bc0[q >> 2];
            float dot1  = fmaf(acc1_1[q], INV_LOSCALE, acc0_1[q]);
            float dist1 = fmaf(-2.0f, dot1, e2c);
            bool  lt1   = dist1 < bestd1[q];
            bestd1[q]   = lt1 ? dist1 : bestd1[q];
            unsigned nv1 = (bc1[q >> 2] & ~(0xFFu << sh)) | ((unsigned)c << sh);
            bc1[q >> 2]  = lt1 ? nv1 : bc1[q >> 2];
        }
    }
#undef STAGE
#undef COMPUTE8
#undef PHASE_SYNC

    // ---- per-wave reduce across 32 code-lanes; write partial keys ----
    #pragma unroll
    for (int m = 0; m < 2; ++m) {
        #pragma unroll
        for (int q = 0; q < 16; ++q) {
            float    d = m ? bestd1[q] : bestd0[q];
            unsigned cc = m ? ((bc1[q >> 2] >> ((q & 3) * 8)) & 0xFFu)
                            : ((bc0[q >> 2] >> ((q & 3) * 8)) & 0xFFu);
            unsigned c = (unsigned)(hw * 2048) + cc * 32u + (unsigned)l31;
            #pragma unroll
            for (int o2 = 16; o2; o2 >>= 1) {
                float    od = __shfl_xor(d, o2);
                unsigned oc = __shfl_xor(c, o2);
                if (od < d || (od == d && oc < c)) { d = od; c = oc; }
            }
            if (l31 == 0) {
                int row = (q & 3) + 8 * (q >> 2) + 4 * hi5 + m * 32;
                unsigned u   = __float_as_uint(d);
                unsigned key = u ^ (unsigned)(((int)u >> 31) | 0x80000000);
                part[(size_t)hw * 32768 + rowbase + row] =
                    ((unsigned long long)key << 32) | c;
            }
        }
    }
}

// combine the two half-K partials -> final float index
__global__ void vq_combine(const unsigned long long* __restrict__ part,
                           float* __restrict__ idxf, int N)
{
    int i = blockIdx.x * blockDim.x + threadIdx.x;
    if (i >= N) return;
    unsigned long long a = part[i];
    unsigned long long b = part[(size_t)N + i];
    unsigned long long m = b < a ? b : a;
    idxf[i] = (float)(unsigned)(m & 0xffffffffu);
}

// ------------------------- round-1 fallback argmin -------------------------
__global__ __launch_bounds__(256, 2) void vq_argmin_f32(
    const float* __restrict__ z, const float* __restrict__ emb,
    const float* __restrict__ e2, float* __restrict__ idxf, int K)
{
    __shared__ float zs[64 * 36];
    __shared__ float es[128 * 36];
    const int t = threadIdx.x;
    const int tx = t & 15;
    const int ty = t >> 4;
    const int rowbase = blockIdx.x * 64;
    const float* zbase = z + (size_t)rowbase * DIM;
    float best[4]; int bidx[4];
    #pragma unroll
    for (int i = 0; i < 4; ++i) { best[i] = 3.4e38f; bidx[i] = 0; }
    for (int kt = 0; kt < K; kt += 128) {
        float acc[4][8];
        #pragma unroll
        for (int i = 0; i < 4; ++i)
            #pragma unroll
            for (int j = 0; j < 8; ++j) acc[i][j] = 0.0f;
        for (int dc = 0; dc < DIM; dc += 32) {
            { int lr = t >> 2, o = (t & 3) * 8;
              const float* gp = zbase + (size_t)lr * DIM + dc + o;
              *(float4*)&zs[lr*36+o]   = *(const float4*)gp;
              *(float4*)&zs[lr*36+o+4] = *(const float4*)(gp+4); }
            { int lc = t >> 1, o = (t & 1) * 16;
              const float* gp = emb + (size_t)(kt+lc) * DIM + dc + o;
              *(float4*)&es[lc*36+o]    = *(const float4*)gp;
              *(float4*)&es[lc*36+o+4]  = *(const float4*)(gp+4);
              *(float4*)&es[lc*36+o+8]  = *(const float4*)(gp+8);
              *(float4*)&es[lc*36+o+12] = *(const float4*)(gp+12); }
            __syncthreads();
            const float* zp = &zs[(ty*4)*36];
            const float* ep = &es[tx*36];
            #pragma unroll
            for (int d = 0; d < 32; d += 4) {
                float4 zv[4], ev[8];
                #pragma unroll
                for (int i = 0; i < 4; ++i) zv[i] = *(const float4*)&zp[i*36+d];
                #pragma unroll
                for (int j = 0; j < 8; ++j) ev[j] = *(const float4*)&ep[j*16*36+d];
                #pragma unroll
                for (int i = 0; i < 4; ++i)
                    #pragma unroll
                    for (int j = 0; j < 8; ++j) {
                        acc[i][j] += zv[i].x*ev[j].x; acc[i][j] += zv[i].y*ev[j].y;
                        acc[i][j] += zv[i].z*ev[j].z; acc[i][j] += zv[i].w*ev[j].w;
                    }
            }
            __syncthreads();
        }
        #pragma unroll
        for (int j = 0; j < 8; ++j) {
            int c = kt + tx + 16*j;
            float ev2 = e2[c];
            #pragma unroll
            for (int i = 0; i < 4; ++i) {
                float dist = ev2 - 2.0f*acc[i][j];
                if (dist < best[i] || (dist == best[i] && c < bidx[i])) { best[i]=dist; bidx[i]=c; }
            }
        }
    }
    #pragma unroll
    for (int i = 0; i < 4; ++i) {
        float bd = best[i]; int bi = bidx[i];
        #pragma unroll
        for (int off = 8; off; off >>= 1) {
            float od = __shfl_xor(bd, off); int oi = __shfl_xor(bi, off);
            if (od < bd || (od == bd && oi < bi)) { bd = od; bi = oi; }
        }
        if (tx == 0) idxf[rowbase + ty*4 + i] = (float)bi;
    }
}

// ------------------------------ epilogue ops -------------------------------
__global__ void vq_gather(const float* __restrict__ emb,
                          const float* __restrict__ idxf,
                          float* __restrict__ zq, int N)
{
    int n = blockIdx.x * 4 + (threadIdx.x >> 6);
    int l = threadIdx.x & 63;
    if (n >= N) return;
    int idx = (int)idxf[n];
    ((float4*)(zq + (size_t)n * DIM))[l] = ((const float4*)(emb + (size_t)idx * DIM))[l];
}

__global__ void vq_hist(const float* __restrict__ idxf, int* __restrict__ counts, int N) {
    int n = blockIdx.x * blockDim.x + threadIdx.x;
    if (n < N) atomicAdd(&counts[(int)idxf[n]], 1);
}

__global__ void vq_ppl(const int* __restrict__ counts, float invN,
                       float* __restrict__ out, int K)
{
    int t = threadIdx.x;
    float s = 0.0f;
    for (int k = t; k < K; k += 256) {
        float p = (float)counts[k] * invN;
        s += p * logf(p + 1e-10f);
    }
    #pragma unroll
    for (int off = 32; off; off >>= 1) s += __shfl_xor(s, off);
    __shared__ float wsum[4];
    if ((t & 63) == 0) wsum[t >> 6] = s;
    __syncthreads();
    if (t == 0) out[0] = expf(-(wsum[0] + wsum[1] + wsum[2] + wsum[3]));
}

extern "C" void kernel_launch(void* const* d_in, const int* in_sizes, int n_in,
                              void* d_out, int out_size, void* d_ws, size_t ws_size,
                              hipStream_t stream)
{
    const float* z   = (const float*)d_in[0];
    const float* emb = (const float*)d_in[1];
    const int N = in_sizes[0] / DIM;   // 32768
    const int K = in_sizes[1] / DIM;   // 4096

    float* out  = (float*)d_out;
    float* zq   = out;
    float* idxf = out + (size_t)N * DIM;
    float* ppl  = idxf + N;

    const size_t PART_BYTES = 2ull * 32768 * sizeof(unsigned long long);  // 512 KB
    const size_t NEED = (size_t)BP_BYTES + 16384 + 16384 + PART_BYTES;

    if (ws_size >= NEED && K == 4096 && N == 32768) {
        f16*   bpk    = (f16*)d_ws;
        float* e2     = (float*)((char*)d_ws + BP_BYTES);
        int*   counts = (int*)((char*)d_ws + BP_BYTES + 16384);
        unsigned long long* part =
            (unsigned long long*)((char*)d_ws + BP_BYTES + 32768);

        vq_pack2<<<1024, 256, 0, stream>>>(emb, bpk);
        vq_e2<<<K, 64, 0, stream>>>(emb, e2);
        vq_zero<<<(K + 255) / 256, 256, 0, stream>>>(counts, K);
        vq_argmin8<<<(N / 256) * 2, 256, 0, stream>>>(z, (const char*)bpk, e2, part);
        vq_combine<<<N / 256, 256, 0, stream>>>(part, idxf, N);
        vq_gather<<<N / 4, 256, 0, stream>>>(emb, idxf, zq, N);
        vq_hist<<<(N + 255) / 256, 256, 0, stream>>>(idxf, counts, N);
        vq_ppl<<<1, 256, 0, stream>>>(counts, 1.0f / (float)N, ppl, K);
    } else {
        float* e2     = (float*)d_ws;
        int*   counts = (int*)((char*)d_ws + (size_t)K * sizeof(float));
        vq_e2<<<K, 64, 0, stream>>>(emb, e2);
        vq_zero<<<(K + 255) / 256, 256, 0, stream>>>(counts, K);
        vq_argmin_f32<<<N / 64, 256, 0, stream>>>(z, emb, e2, idxf, K);
        vq_gather<<<N / 4, 256, 0, stream>>>(emb, idxf, zq, N);
        vq_hist<<<(N + 255) / 256, 256, 0, stream>>>(idxf, counts, N);
        vq_ppl<<<1, 256, 0, stream>>>(counts, 1.0f / (float)N, ppl, K);
    }
}

// Round 10
// 223.508 us; speedup vs baseline: 1.1075x; 1.1075x over previous
//
#include <hip/hip_runtime.h>
#include <hip/hip_bf16.h>
#include <math.h>
#include <stdint.h>

typedef _Float16 f16;
typedef _Float16 f16x8 __attribute__((ext_vector_type(8)));
typedef float f32x16 __attribute__((ext_vector_type(16)));

#define DIM 256
#define LOSCALE 2048.0f
#define INV_LOSCALE (1.0f/2048.0f)

// B' stream: 4096 codes x 256 depth x {hi,lo}, fragment-major:
// byte offset = col*32768 + s*2048 + t*1024 + lane*16
// (col 0..127 = 32 codes each, k-step s 0..15, t 0:hi 1:lo)
// lane l holds 16B = e[code=col*32+(l&31)][depth=s*16+(l>>5)*8 .. +8]
// 96KB pad: uniform staging runs 2 cols past each half's end.
#define BP_BYTES (4096u*1024u + 98304u)

#define GLOAD16(gp, lp) __builtin_amdgcn_global_load_lds( \
    (const __attribute__((address_space(1))) void*)(gp),  \
    (__attribute__((address_space(3))) void*)(lp), 16, 0, 0)

// ---------------------------------------------------------------------------
// pack codebook into fragment-major hi/lo f16 stream
// ---------------------------------------------------------------------------
__global__ void vq_pack2(const float* __restrict__ emb, f16* __restrict__ bp)
{
    int o = blockIdx.x * blockDim.x + threadIdx.x;   // one per 16B chunk, 262144
    int l = o & 63;
    int b = o >> 6;
    int t   = b & 1;
    int s   = (b >> 1) & 15;
    int col = b >> 5;
    int code  = col * 32 + (l & 31);
    int depth = s * 16 + (l >> 5) * 8;
    const float* gp = emb + (size_t)code * DIM + depth;
    float4 x0 = *(const float4*)gp;
    float4 x1 = *(const float4*)(gp + 4);
    float xs[8] = {x0.x, x0.y, x0.z, x0.w, x1.x, x1.y, x1.z, x1.w};
    f16x8 v;
    #pragma unroll
    for (int j = 0; j < 8; ++j) {
        f16 h = (f16)xs[j];
        v[j] = t ? (f16)((xs[j] - (float)h) * LOSCALE) : h;
    }
    *(f16x8*)(bp + (size_t)o * 8) = v;
}

// ||e_k||^2, one 64-thread block per code (fp32, full precision)
__global__ void vq_e2(const float* __restrict__ emb, float* __restrict__ e2) {
    int k = blockIdx.x;
    int l = threadIdx.x;
    float4 v = ((const float4*)(emb + (size_t)k * DIM))[l];
    float s = v.x * v.x + v.y * v.y + v.z * v.z + v.w * v.w;
    #pragma unroll
    for (int off = 32; off; off >>= 1) s += __shfl_xor(s, off);
    if (l == 0) e2[k] = s;
}

__global__ void vq_zero(int* __restrict__ p, int n) {
    int i = blockIdx.x * blockDim.x + threadIdx.x;
    if (i < n) p[i] = 0;
}

// ---------------------------------------------------------------------------
// MFMA argmin: full-col units, 1 barrier per col (64 total).
// 512 thr = 8 waves x 32 rows = 256 rows/block, one code half (64 cols).
// 2 waves/SIMD (LB 512,2). 4 x 32KB LDS buffers, counted vmcnt(8), raw
// s_barrier. Per col per wave: 32 ds_read_b128 -> 48 MFMA (3 indep chains).
// ---------------------------------------------------------------------------
__global__ __launch_bounds__(512, 2) void vq_argmin9(
    const float* __restrict__ z, const char* __restrict__ bp,
    const float* __restrict__ e2, unsigned long long* __restrict__ part)
{
    __shared__ __align__(16) char bufs[4][32768];   // 128 KB
    __shared__ float e2s[2048];                     // 8 KB

    const int t    = threadIdx.x;
    const int lane = t & 63;
    const int wv   = t >> 6;               // wave 0..7
    const int hw   = blockIdx.x & 1;       // code half
    const int rg   = blockIdx.x >> 1;      // row group (256 rows)
    const int l31  = lane & 31;
    const int hi5  = lane >> 5;
    const int rowbase = rg * 256 + wv * 32;

    // ---- e2 half to LDS ----
    *(float4*)&e2s[t * 4] = *(const float4*)(e2 + hw * 2048 + t * 4);

    // ---- A panel (32 rows) to registers, hi/lo split ----
    f16x8 a_h[16], a_l[16];
    {
        const float* zr = z + (size_t)(rowbase + l31) * DIM + hi5 * 8;
        #pragma unroll
        for (int s = 0; s < 16; ++s) {
            float4 x0 = *(const float4*)(zr + s * 16);
            float4 x1 = *(const float4*)(zr + s * 16 + 4);
            float xs[8] = {x0.x, x0.y, x0.z, x0.w, x1.x, x1.y, x1.z, x1.w};
            #pragma unroll
            for (int j = 0; j < 8; ++j) {
                f16 h = (f16)xs[j];
                a_h[s][j] = h;
                a_l[s][j] = (f16)((xs[j] - (float)h) * LOSCALE);
            }
        }
    }

    const char* bhalf = bp + ((size_t)hw << 21);   // 2 MB half

    // stage col cc (32KB) into buffer pb: 512 thr x 4 x 16B, linear
#define STAGE(pb, cc) do {                                                    \
    const char* src_ = bhalf + ((size_t)(cc) << 15) + (size_t)t * 16;         \
    char* dst_ = bufs[pb] + t * 16;                                           \
    _Pragma("unroll")                                                         \
    for (int i_ = 0; i_ < 4; ++i_)                                            \
        GLOAD16(src_ + i_ * 8192, dst_ + i_ * 8192);                          \
    } while (0)

    STAGE(0, 0);
    STAGE(1, 1);
    __syncthreads();   // full drain once: cols 0,1 staged; e2s visible

    float    bestd[16];
    unsigned bcol[4];
    #pragma unroll
    for (int q = 0; q < 16; ++q) bestd[q] = 3.4e38f;
    #pragma unroll
    for (int i = 0; i < 4; ++i) bcol[i] = 0u;

    for (int c = 0; c < 64; ++c) {
        // stage col c+2 into the buffer last read at col c-2 (race-free:
        // every wave passed barrier c-1, which implies COMPUTE(c-2) done)
        STAGE((c + 2) & 3, c + 2);

        asm volatile("s_waitcnt vmcnt(8)" ::: "memory");   // col c's 4 done
        asm volatile("s_waitcnt lgkmcnt(0)" ::: "memory");
        __builtin_amdgcn_s_barrier();
        __builtin_amdgcn_sched_barrier(0);

        f32x16 acc0, acc1a, acc1b;
        #pragma unroll
        for (int q = 0; q < 16; ++q) { acc0[q] = 0.0f; acc1a[q] = 0.0f; acc1b[q] = 0.0f; }

        const char* bb = bufs[c & 3];
        f16x8 bh_ = *(const f16x8*)(bb + lane * 16);
        f16x8 bl_ = *(const f16x8*)(bb + 1024 + lane * 16);
        __builtin_amdgcn_s_setprio(1);
        #pragma unroll
        for (int ks = 0; ks < 16; ++ks) {
            f16x8 bhn_, bln_;
            if (ks < 15) {
                bhn_ = *(const f16x8*)(bb + (ks + 1) * 2048 + lane * 16);
                bln_ = *(const f16x8*)(bb + (ks + 1) * 2048 + 1024 + lane * 16);
            }
            acc0  = __builtin_amdgcn_mfma_f32_32x32x16_f16(a_h[ks], bh_, acc0,  0, 0, 0);
            acc1a = __builtin_amdgcn_mfma_f32_32x32x16_f16(a_h[ks], bl_, acc1a, 0, 0, 0);
            acc1b = __builtin_amdgcn_mfma_f32_32x32x16_f16(a_l[ks], bh_, acc1b, 0, 0, 0);
            if (ks < 15) { bh_ = bhn_; bl_ = bln_; }
        }
        __builtin_amdgcn_s_setprio(0);

        // epilogue: fold scales, distances, running argmin
        float e2c = e2s[c * 32 + l31];
        #pragma unroll
        for (int q = 0; q < 16; ++q) {
            float dot  = fmaf(acc1a[q] + acc1b[q], INV_LOSCALE, acc0[q]);
            float dist = fmaf(-2.0f, dot, e2c);
            bool  lt   = dist < bestd[q];
            bestd[q]   = lt ? dist : bestd[q];
            const unsigned sh = (unsigned)((q & 3) * 8);
            unsigned nv = (bcol[q >> 2] & ~(0xFFu << sh)) | ((unsigned)c << sh);
            bcol[q >> 2] = lt ? nv : bcol[q >> 2];
        }
    }
#undef STAGE

    // ---- per-wave reduce across 32 code-lanes; write partial keys ----
    #pragma unroll
    for (int q = 0; q < 16; ++q) {
        float    d = bestd[q];
        unsigned c = (unsigned)(hw * 2048) +
                     ((bcol[q >> 2] >> ((q & 3) * 8)) & 0xFFu) * 32u + (unsigned)l31;
        #pragma unroll
        for (int o2 = 16; o2; o2 >>= 1) {
            float    od = __shfl_xor(d, o2);
            unsigned oc = __shfl_xor(c, o2);
            if (od < d || (od == d && oc < c)) { d = od; c = oc; }
        }
        if (l31 == 0) {
            int row = (q & 3) + 8 * (q >> 2) + 4 * hi5;
            unsigned u   = __float_as_uint(d);
            unsigned key = u ^ (unsigned)(((int)u >> 31) | 0x80000000);
            part[(size_t)hw * 32768 + rowbase + row] =
                ((unsigned long long)key << 32) | c;
        }
    }
}

// fused: combine half-K partials -> idx, gather z_q row, histogram
__global__ void vq_final(const unsigned long long* __restrict__ part,
                         const float* __restrict__ emb,
                         float* __restrict__ idxf, float* __restrict__ zq,
                         int* __restrict__ counts, int N)
{
    int n = blockIdx.x * 4 + (threadIdx.x >> 6);
    int l = threadIdx.x & 63;
    if (n >= N) return;
    unsigned long long a = part[n];
    unsigned long long b = part[(size_t)N + n];
    unsigned long long m = b < a ? b : a;
    int idx = (int)(unsigned)(m & 0xffffffffu);
    ((float4*)(zq + (size_t)n * DIM))[l] =
        ((const float4*)(emb + (size_t)idx * DIM))[l];
    if (l == 0) {
        idxf[n] = (float)idx;
        atomicAdd(&counts[idx], 1);
    }
}

// ------------------------- round-1 fallback argmin -------------------------
__global__ __launch_bounds__(256, 2) void vq_argmin_f32(
    const float* __restrict__ z, const float* __restrict__ emb,
    const float* __restrict__ e2, float* __restrict__ idxf, int K)
{
    __shared__ float zs[64 * 36];
    __shared__ float es[128 * 36];
    const int t = threadIdx.x;
    const int tx = t & 15;
    const int ty = t >> 4;
    const int rowbase = blockIdx.x * 64;
    const float* zbase = z + (size_t)rowbase * DIM;
    float best[4]; int bidx[4];
    #pragma unroll
    for (int i = 0; i < 4; ++i) { best[i] = 3.4e38f; bidx[i] = 0; }
    for (int kt = 0; kt < K; kt += 128) {
        float acc[4][8];
        #pragma unroll
        for (int i = 0; i < 4; ++i)
            #pragma unroll
            for (int j = 0; j < 8; ++j) acc[i][j] = 0.0f;
        for (int dc = 0; dc < DIM; dc += 32) {
            { int lr = t >> 2, o = (t & 3) * 8;
              const float* gp = zbase + (size_t)lr * DIM + dc + o;
              *(float4*)&zs[lr*36+o]   = *(const float4*)gp;
              *(float4*)&zs[lr*36+o+4] = *(const float4*)(gp+4); }
            { int lc = t >> 1, o = (t & 1) * 16;
              const float* gp = emb + (size_t)(kt+lc) * DIM + dc + o;
              *(float4*)&es[lc*36+o]    = *(const float4*)gp;
              *(float4*)&es[lc*36+o+4]  = *(const float4*)(gp+4);
              *(float4*)&es[lc*36+o+8]  = *(const float4*)(gp+8);
              *(float4*)&es[lc*36+o+12] = *(const float4*)(gp+12); }
            __syncthreads();
            const float* zp = &zs[(ty*4)*36];
            const float* ep = &es[tx*36];
            #pragma unroll
            for (int d = 0; d < 32; d += 4) {
                float4 zv[4], ev[8];
                #pragma unroll
                for (int i = 0; i < 4; ++i) zv[i] = *(const float4*)&zp[i*36+d];
                #pragma unroll
                for (int j = 0; j < 8; ++j) ev[j] = *(const float4*)&ep[j*16*36+d];
                #pragma unroll
                for (int i = 0; i < 4; ++i)
                    #pragma unroll
                    for (int j = 0; j < 8; ++j) {
                        acc[i][j] += zv[i].x*ev[j].x; acc[i][j] += zv[i].y*ev[j].y;
                        acc[i][j] += zv[i].z*ev[j].z; acc[i][j] += zv[i].w*ev[j].w;
                    }
            }
            __syncthreads();
        }
        #pragma unroll
        for (int j = 0; j < 8; ++j) {
            int c = kt + tx + 16*j;
            float ev2 = e2[c];
            #pragma unroll
            for (int i = 0; i < 4; ++i) {
                float dist = ev2 - 2.0f*acc[i][j];
                if (dist < best[i] || (dist == best[i] && c < bidx[i])) { best[i]=dist; bidx[i]=c; }
            }
        }
    }
    #pragma unroll
    for (int i = 0; i < 4; ++i) {
        float bd = best[i]; int bi = bidx[i];
        #pragma unroll
        for (int off = 8; off; off >>= 1) {
            float od = __shfl_xor(bd, off); int oi = __shfl_xor(bi, off);
            if (od < bd || (od == bd && oi < bi)) { bd = od; bi = oi; }
        }
        if (tx == 0) idxf[rowbase + ty*4 + i] = (float)bi;
    }
}

// ------------------------------ epilogue ops -------------------------------
__global__ void vq_gather(const float* __restrict__ emb,
                          const float* __restrict__ idxf,
                          float* __restrict__ zq, int N)
{
    int n = blockIdx.x * 4 + (threadIdx.x >> 6);
    int l = threadIdx.x & 63;
    if (n >= N) return;
    int idx = (int)idxf[n];
    ((float4*)(zq + (size_t)n * DIM))[l] = ((const float4*)(emb + (size_t)idx * DIM))[l];
}

__global__ void vq_hist(const float* __restrict__ idxf, int* __restrict__ counts, int N) {
    int n = blockIdx.x * blockDim.x + threadIdx.x;
    if (n < N) atomicAdd(&counts[(int)idxf[n]], 1);
}

__global__ void vq_ppl(const int* __restrict__ counts, float invN,
                       float* __restrict__ out, int K)
{
    int t = threadIdx.x;
    float s = 0.0f;
    for (int k = t; k < K; k += 256) {
        float p = (float)counts[k] * invN;
        s += p * logf(p + 1e-10f);
    }
    #pragma unroll
    for (int off = 32; off; off >>= 1) s += __shfl_xor(s, off);
    __shared__ float wsum[4];
    if ((t & 63) == 0) wsum[t >> 6] = s;
    __syncthreads();
    if (t == 0) out[0] = expf(-(wsum[0] + wsum[1] + wsum[2] + wsum[3]));
}

extern "C" void kernel_launch(void* const* d_in, const int* in_sizes, int n_in,
                              void* d_out, int out_size, void* d_ws, size_t ws_size,
                              hipStream_t stream)
{
    const float* z   = (const float*)d_in[0];
    const float* emb = (const float*)d_in[1];
    const int N = in_sizes[0] / DIM;   // 32768
    const int K = in_sizes[1] / DIM;   // 4096

    float* out  = (float*)d_out;
    float* zq   = out;
    float* idxf = out + (size_t)N * DIM;
    float* ppl  = idxf + N;

    const size_t PART_BYTES = 2ull * 32768 * sizeof(unsigned long long);  // 512 KB
    const size_t NEED = (size_t)BP_BYTES + 16384 + 16384 + PART_BYTES;

    if (ws_size >= NEED && K == 4096 && N == 32768) {
        f16*   bpk    = (f16*)d_ws;
        float* e2     = (float*)((char*)d_ws + BP_BYTES);
        int*   counts = (int*)((char*)d_ws + BP_BYTES + 16384);
        unsigned long long* part =
            (unsigned long long*)((char*)d_ws + BP_BYTES + 32768);

        vq_pack2<<<1024, 256, 0, stream>>>(emb, bpk);
        vq_e2<<<K, 64, 0, stream>>>(emb, e2);
        vq_zero<<<(K + 255) / 256, 256, 0, stream>>>(counts, K);
        vq_argmin9<<<(N / 256) * 2, 512, 0, stream>>>(z, (const char*)bpk, e2, part);
        vq_final<<<N / 4, 256, 0, stream>>>(part, emb, idxf, zq, counts, N);
        vq_ppl<<<1, 256, 0, stream>>>(counts, 1.0f / (float)N, ppl, K);
    } else {
        float* e2     = (float*)d_ws;
        int*   counts = (int*)((char*)d_ws + (size_t)K * sizeof(float));
        vq_e2<<<K, 64, 0, stream>>>(emb, e2);
        vq_zero<<<(K + 255) / 256, 256, 0, stream>>>(counts, K);
        vq_argmin_f32<<<N / 64, 256, 0, stream>>>(z, emb, e2, idxf, K);
        vq_gather<<<N / 4, 256, 0, stream>>>(emb, idxf, zq, N);
        vq_hist<<<(N + 255) / 256, 256, 0, stream>>>(idxf, counts, N);
        vq_ppl<<<1, 256, 0, stream>>>(counts, 1.0f / (float)N, ppl, K);
    }
}

// Round 11
// 223.493 us; speedup vs baseline: 1.1075x; 1.0001x over previous
//
#include <hip/hip_runtime.h>
#include <hip/hip_bf16.h>
#include <math.h>
#include <stdint.h>

typedef _Float16 f16;
typedef _Float16 f16x8 __attribute__((ext_vector_type(8)));
typedef float f32x16 __attribute__((ext_vector_type(16)));

#define DIM 256
#define LOSCALE 2048.0f
#define INV_LOSCALE (1.0f/2048.0f)

// B' stream: 4096 codes x 256 depth x {hi,lo}, fragment-major:
// byte offset = col*32768 + s*2048 + t*1024 + lane*16
// (col 0..127 = 32 codes each, k-step s 0..15, t 0:hi 1:lo)
// lane l holds 16B = e[code=col*32+(l&31)][depth=s*16+(l>>5)*8 .. +8]
// 96KB pad: uniform staging runs 2 cols past each half's end.
#define BP_BYTES (4096u*1024u + 98304u)

#define GLOAD16(gp, lp) __builtin_amdgcn_global_load_lds( \
    (const __attribute__((address_space(1))) void*)(gp),  \
    (__attribute__((address_space(3))) void*)(lp), 16, 0, 0)

// ---------------------------------------------------------------------------
// pack codebook into fragment-major hi/lo f16 stream
// ---------------------------------------------------------------------------
__global__ void vq_pack2(const float* __restrict__ emb, f16* __restrict__ bp)
{
    int o = blockIdx.x * blockDim.x + threadIdx.x;   // one per 16B chunk, 262144
    int l = o & 63;
    int b = o >> 6;
    int t   = b & 1;
    int s   = (b >> 1) & 15;
    int col = b >> 5;
    int code  = col * 32 + (l & 31);
    int depth = s * 16 + (l >> 5) * 8;
    const float* gp = emb + (size_t)code * DIM + depth;
    float4 x0 = *(const float4*)gp;
    float4 x1 = *(const float4*)(gp + 4);
    float xs[8] = {x0.x, x0.y, x0.z, x0.w, x1.x, x1.y, x1.z, x1.w};
    f16x8 v;
    #pragma unroll
    for (int j = 0; j < 8; ++j) {
        f16 h = (f16)xs[j];
        v[j] = t ? (f16)((xs[j] - (float)h) * LOSCALE) : h;
    }
    *(f16x8*)(bp + (size_t)o * 8) = v;
}

// ||e_k||^2, one 64-thread block per code (fp32, full precision)
__global__ void vq_e2(const float* __restrict__ emb, float* __restrict__ e2) {
    int k = blockIdx.x;
    int l = threadIdx.x;
    float4 v = ((const float4*)(emb + (size_t)k * DIM))[l];
    float s = v.x * v.x + v.y * v.y + v.z * v.z + v.w * v.w;
    #pragma unroll
    for (int off = 32; off; off >>= 1) s += __shfl_xor(s, off);
    if (l == 0) e2[k] = s;
}

__global__ void vq_zero(int* __restrict__ p, int n) {
    int i = blockIdx.x * blockDim.x + threadIdx.x;
    if (i < n) p[i] = 0;
}

// ---------------------------------------------------------------------------
// MFMA argmin: full-col units, 1 barrier per col, 4-deep B-read pipeline.
// 512 thr = 8 waves x 32 rows = 256 rows/block, one code half (64 cols).
// 2 waves/SIMD. 4 x 32KB LDS buffers, counted vmcnt(8), raw s_barrier.
// Inner loop keeps 4 k-steps of B fragments in flight (96 cyc MFMA cover
// per wave vs ~120 cyc LDS latency; x2 waves/SIMD hides the rest).
// ---------------------------------------------------------------------------
__global__ __launch_bounds__(512, 2) void vq_argmin10(
    const float* __restrict__ z, const char* __restrict__ bp,
    const float* __restrict__ e2, unsigned long long* __restrict__ part)
{
    __shared__ __align__(16) char bufs[4][32768];   // 128 KB
    __shared__ float e2s[2048];                     // 8 KB

    const int t    = threadIdx.x;
    const int lane = t & 63;
    const int wv   = t >> 6;               // wave 0..7
    const int hw   = blockIdx.x & 1;       // code half
    const int rg   = blockIdx.x >> 1;      // row group (256 rows)
    const int l31  = lane & 31;
    const int hi5  = lane >> 5;
    const int rowbase = rg * 256 + wv * 32;

    // ---- e2 half to LDS ----
    *(float4*)&e2s[t * 4] = *(const float4*)(e2 + hw * 2048 + t * 4);

    // ---- A panel (32 rows) to registers, hi/lo split ----
    f16x8 a_h[16], a_l[16];
    {
        const float* zr = z + (size_t)(rowbase + l31) * DIM + hi5 * 8;
        #pragma unroll
        for (int s = 0; s < 16; ++s) {
            float4 x0 = *(const float4*)(zr + s * 16);
            float4 x1 = *(const float4*)(zr + s * 16 + 4);
            float xs[8] = {x0.x, x0.y, x0.z, x0.w, x1.x, x1.y, x1.z, x1.w};
            #pragma unroll
            for (int j = 0; j < 8; ++j) {
                f16 h = (f16)xs[j];
                a_h[s][j] = h;
                a_l[s][j] = (f16)((xs[j] - (float)h) * LOSCALE);
            }
        }
    }

    const char* bhalf = bp + ((size_t)hw << 21);   // 2 MB half

    // stage col cc (32KB) into buffer pb: 512 thr x 4 x 16B, linear
#define STAGE(pb, cc) do {                                                    \
    const char* src_ = bhalf + ((size_t)(cc) << 15) + (size_t)t * 16;         \
    char* dst_ = bufs[pb] + t * 16;                                           \
    _Pragma("unroll")                                                         \
    for (int i_ = 0; i_ < 4; ++i_)                                            \
        GLOAD16(src_ + i_ * 8192, dst_ + i_ * 8192);                          \
    } while (0)

    STAGE(0, 0);
    STAGE(1, 1);
    __syncthreads();   // full drain once: cols 0,1 staged; e2s visible

    float    bestd[16];
    unsigned bcol[4];
    #pragma unroll
    for (int q = 0; q < 16; ++q) bestd[q] = 3.4e38f;
    #pragma unroll
    for (int i = 0; i < 4; ++i) bcol[i] = 0u;

    for (int c = 0; c < 64; ++c) {
        // stage col c+2 into the buffer last read at col c-2 (race-free:
        // every wave passed barrier c-1, which implies COMPUTE(c-2) done)
        STAGE((c + 2) & 3, c + 2);

        asm volatile("s_waitcnt vmcnt(8)" ::: "memory");   // col c's 4 done
        asm volatile("s_waitcnt lgkmcnt(0)" ::: "memory");
        __builtin_amdgcn_s_barrier();
        __builtin_amdgcn_sched_barrier(0);

        f32x16 acc0, acc1a, acc1b;
        #pragma unroll
        for (int q = 0; q < 16; ++q) { acc0[q] = 0.0f; acc1a[q] = 0.0f; acc1b[q] = 0.0f; }

        const char* bb = bufs[c & 3];

        // ---- 4-deep B fragment pipeline ----
        f16x8 ph[4], pl[4];
        #pragma unroll
        for (int i = 0; i < 4; ++i) {
            ph[i] = *(const f16x8*)(bb + i * 2048 + lane * 16);
            pl[i] = *(const f16x8*)(bb + i * 2048 + 1024 + lane * 16);
        }
        __builtin_amdgcn_s_setprio(1);
        #pragma unroll
        for (int ks = 0; ks < 16; ++ks) {
            f16x8 bh_ = ph[ks & 3];
            f16x8 bl_ = pl[ks & 3];
            if (ks + 4 < 16) {   // refill slot with k-step ks+4
                ph[ks & 3] = *(const f16x8*)(bb + (ks + 4) * 2048 + lane * 16);
                pl[ks & 3] = *(const f16x8*)(bb + (ks + 4) * 2048 + 1024 + lane * 16);
            }
            acc0  = __builtin_amdgcn_mfma_f32_32x32x16_f16(a_h[ks], bh_, acc0,  0, 0, 0);
            acc1a = __builtin_amdgcn_mfma_f32_32x32x16_f16(a_h[ks], bl_, acc1a, 0, 0, 0);
            acc1b = __builtin_amdgcn_mfma_f32_32x32x16_f16(a_l[ks], bh_, acc1b, 0, 0, 0);
        }
        __builtin_amdgcn_s_setprio(0);

        // epilogue: fold scales, distances, running argmin
        float e2c = e2s[c * 32 + l31];
        #pragma unroll
        for (int q = 0; q < 16; ++q) {
            float dot  = fmaf(acc1a[q] + acc1b[q], INV_LOSCALE, acc0[q]);
            float dist = fmaf(-2.0f, dot, e2c);
            bool  lt   = dist < bestd[q];
            bestd[q]   = lt ? dist : bestd[q];
            const unsigned sh = (unsigned)((q & 3) * 8);
            unsigned nv = (bcol[q >> 2] & ~(0xFFu << sh)) | ((unsigned)c << sh);
            bcol[q >> 2] = lt ? nv : bcol[q >> 2];
        }
    }
#undef STAGE

    // ---- per-wave reduce across 32 code-lanes; write partial keys ----
    #pragma unroll
    for (int q = 0; q < 16; ++q) {
        float    d = bestd[q];
        unsigned c = (unsigned)(hw * 2048) +
                     ((bcol[q >> 2] >> ((q & 3) * 8)) & 0xFFu) * 32u + (unsigned)l31;
        #pragma unroll
        for (int o2 = 16; o2; o2 >>= 1) {
            float    od = __shfl_xor(d, o2);
            unsigned oc = __shfl_xor(c, o2);
            if (od < d || (od == d && oc < c)) { d = od; c = oc; }
        }
        if (l31 == 0) {
            int row = (q & 3) + 8 * (q >> 2) + 4 * hi5;
            unsigned u   = __float_as_uint(d);
            unsigned key = u ^ (unsigned)(((int)u >> 31) | 0x80000000);
            part[(size_t)hw * 32768 + rowbase + row] =
                ((unsigned long long)key << 32) | c;
        }
    }
}

// fused: combine half-K partials -> idx, gather z_q row, histogram
__global__ void vq_final(const unsigned long long* __restrict__ part,
                         const float* __restrict__ emb,
                         float* __restrict__ idxf, float* __restrict__ zq,
                         int* __restrict__ counts, int N)
{
    int n = blockIdx.x * 4 + (threadIdx.x >> 6);
    int l = threadIdx.x & 63;
    if (n >= N) return;
    unsigned long long a = part[n];
    unsigned long long b = part[(size_t)N + n];
    unsigned long long m = b < a ? b : a;
    int idx = (int)(unsigned)(m & 0xffffffffu);
    ((float4*)(zq + (size_t)n * DIM))[l] =
        ((const float4*)(emb + (size_t)idx * DIM))[l];
    if (l == 0) {
        idxf[n] = (float)idx;
        atomicAdd(&counts[idx], 1);
    }
}

// ------------------------- round-1 fallback argmin -------------------------
__global__ __launch_bounds__(256, 2) void vq_argmin_f32(
    const float* __restrict__ z, const float* __restrict__ emb,
    const float* __restrict__ e2, float* __restrict__ idxf, int K)
{
    __shared__ float zs[64 * 36];
    __shared__ float es[128 * 36];
    const int t = threadIdx.x;
    const int tx = t & 15;
    const int ty = t >> 4;
    const int rowbase = blockIdx.x * 64;
    const float* zbase = z + (size_t)rowbase * DIM;
    float best[4]; int bidx[4];
    #pragma unroll
    for (int i = 0; i < 4; ++i) { best[i] = 3.4e38f; bidx[i] = 0; }
    for (int kt = 0; kt < K; kt += 128) {
        float acc[4][8];
        #pragma unroll
        for (int i = 0; i < 4; ++i)
            #pragma unroll
            for (int j = 0; j < 8; ++j) acc[i][j] = 0.0f;
        for (int dc = 0; dc < DIM; dc += 32) {
            { int lr = t >> 2, o = (t & 3) * 8;
              const float* gp = zbase + (size_t)lr * DIM + dc + o;
              *(float4*)&zs[lr*36+o]   = *(const float4*)gp;
              *(float4*)&zs[lr*36+o+4] = *(const float4*)(gp+4); }
            { int lc = t >> 1, o = (t & 1) * 16;
              const float* gp = emb + (size_t)(kt+lc) * DIM + dc + o;
              *(float4*)&es[lc*36+o]    = *(const float4*)gp;
              *(float4*)&es[lc*36+o+4]  = *(const float4*)(gp+4);
              *(float4*)&es[lc*36+o+8]  = *(const float4*)(gp+8);
              *(float4*)&es[lc*36+o+12] = *(const float4*)(gp+12); }
            __syncthreads();
            const float* zp = &zs[(ty*4)*36];
            const float* ep = &es[tx*36];
            #pragma unroll
            for (int d = 0; d < 32; d += 4) {
                float4 zv[4], ev[8];
                #pragma unroll
                for (int i = 0; i < 4; ++i) zv[i] = *(const float4*)&zp[i*36+d];
                #pragma unroll
                for (int j = 0; j < 8; ++j) ev[j] = *(const float4*)&ep[j*16*36+d];
                #pragma unroll
                for (int i = 0; i < 4; ++i)
                    #pragma unroll
                    for (int j = 0; j < 8; ++j) {
                        acc[i][j] += zv[i].x*ev[j].x; acc[i][j] += zv[i].y*ev[j].y;
                        acc[i][j] += zv[i].z*ev[j].z; acc[i][j] += zv[i].w*ev[j].w;
                    }
            }
            __syncthreads();
        }
        #pragma unroll
        for (int j = 0; j < 8; ++j) {
            int c = kt + tx + 16*j;
            float ev2 = e2[c];
            #pragma unroll
            for (int i = 0; i < 4; ++i) {
                float dist = ev2 - 2.0f*acc[i][j];
                if (dist < best[i] || (dist == best[i] && c < bidx[i])) { best[i]=dist; bidx[i]=c; }
            }
        }
    }
    #pragma unroll
    for (int i = 0; i < 4; ++i) {
        float bd = best[i]; int bi = bidx[i];
        #pragma unroll
        for (int off = 8; off; off >>= 1) {
            float od = __shfl_xor(bd, off); int oi = __shfl_xor(bi, off);
            if (od < bd || (od == bd && oi < bi)) { bd = od; bi = oi; }
        }
        if (tx == 0) idxf[rowbase + ty*4 + i] = (float)bi;
    }
}

// ------------------------------ epilogue ops -------------------------------
__global__ void vq_gather(const float* __restrict__ emb,
                          const float* __restrict__ idxf,
                          float* __restrict__ zq, int N)
{
    int n = blockIdx.x * 4 + (threadIdx.x >> 6);
    int l = threadIdx.x & 63;
    if (n >= N) return;
    int idx = (int)idxf[n];
    ((float4*)(zq + (size_t)n * DIM))[l] = ((const float4*)(emb + (size_t)idx * DIM))[l];
}

__global__ void vq_hist(const float* __restrict__ idxf, int* __restrict__ counts, int N) {
    int n = blockIdx.x * blockDim.x + threadIdx.x;
    if (n < N) atomicAdd(&counts[(int)idxf[n]], 1);
}

__global__ void vq_ppl(const int* __restrict__ counts, float invN,
                       float* __restrict__ out, int K)
{
    int t = threadIdx.x;
    float s = 0.0f;
    for (int k = t; k < K; k += 256) {
        float p = (float)counts[k] * invN;
        s += p * logf(p + 1e-10f);
    }
    #pragma unroll
    for (int off = 32; off; off >>= 1) s += __shfl_xor(s, off);
    __shared__ float wsum[4];
    if ((t & 63) == 0) wsum[t >> 6] = s;
    __syncthreads();
    if (t == 0) out[0] = expf(-(wsum[0] + wsum[1] + wsum[2] + wsum[3]));
}

extern "C" void kernel_launch(void* const* d_in, const int* in_sizes, int n_in,
                              void* d_out, int out_size, void* d_ws, size_t ws_size,
                              hipStream_t stream)
{
    const float* z   = (const float*)d_in[0];
    const float* emb = (const float*)d_in[1];
    const int N = in_sizes[0] / DIM;   // 32768
    const int K = in_sizes[1] / DIM;   // 4096

    float* out  = (float*)d_out;
    float* zq   = out;
    float* idxf = out + (size_t)N * DIM;
    float* ppl  = idxf + N;

    const size_t PART_BYTES = 2ull * 32768 * sizeof(unsigned long long);  // 512 KB
    const size_t NEED = (size_t)BP_BYTES + 16384 + 16384 + PART_BYTES;

    if (ws_size >= NEED && K == 4096 && N == 32768) {
        f16*   bpk    = (f16*)d_ws;
        float* e2     = (float*)((char*)d_ws + BP_BYTES);
        int*   counts = (int*)((char*)d_ws + BP_BYTES + 16384);
        unsigned long long* part =
            (unsigned long long*)((char*)d_ws + BP_BYTES + 32768);

        vq_pack2<<<1024, 256, 0, stream>>>(emb, bpk);
        vq_e2<<<K, 64, 0, stream>>>(emb, e2);
        vq_zero<<<(K + 255) / 256, 256, 0, stream>>>(counts, K);
        vq_argmin10<<<(N / 256) * 2, 512, 0, stream>>>(z, (const char*)bpk, e2, part);
        vq_final<<<N / 4, 256, 0, stream>>>(part, emb, idxf, zq, counts, N);
        vq_ppl<<<1, 256, 0, stream>>>(counts, 1.0f / (float)N, ppl, K);
    } else {
        float* e2     = (float*)d_ws;
        int*   counts = (int*)((char*)d_ws + (size_t)K * sizeof(float));
        vq_e2<<<K, 64, 0, stream>>>(emb, e2);
        vq_zero<<<(K + 255) / 256, 256, 0, stream>>>(counts, K);
        vq_argmin_f32<<<N / 64, 256, 0, stream>>>(z, emb, e2, idxf, K);
        vq_gather<<<N / 4, 256, 0, stream>>>(emb, idxf, zq, N);
        vq_hist<<<(N + 255) / 256, 256, 0, stream>>>(idxf, counts, N);
        vq_ppl<<<1, 256, 0, stream>>>(counts, 1.0f / (float)N, ppl, K);
    }
}